// Round 3
// baseline (250.936 us; speedup 1.0000x reference)
//
#include <hip/hip_runtime.h>

// Output layout (float32, concatenated flat in reference return order):
//   [0]                image        64*3*416*416 = 33,226,752
//   [IMG_ELEMS]        targets@13   64*13*13*25  =    270,400
//   [.. + 270400]      targets@26   64*26*26*25  =  1,081,600
//   [.. + 1352000]     targets@52   64*52*52*25  =  4,326,400
#define IMG_ELEMS (64 * 3 * 416 * 416)
#define CELLS_PER_IMG (13*13 + 26*26 + 52*52)   // 3549
#define BASE13 0
#define BASE26 (64 * 169 * 25)                  // 270400
#define BASE52 (BASE26 + 64 * 676 * 25)         // 1352000

// Fused grid, "copy sandwich" scheduling:
//   [0, COPY_HALF1)                 copy blocks  — saturate HBM immediately
//   [COPY_HALF1, +ASSIGN_BLOCKS)    assign blocks — drain in the shadow of copy
//   [.., TOTAL)                     copy blocks  — no divergent tail
// VPT=2 (16 KB r+w per block): fine tail granularity — 17120 blocks, residual
// block-wave quantum ~0.7 µs instead of ~2.8 µs at VPT=8.
#define ASSIGN_CHUNKS 14                        // ceil(3549/256)
#define ASSIGN_BLOCKS (64 * ASSIGN_CHUNKS)      // 896
#define N4 (IMG_ELEMS / 4)                      // 8,306,688 16B-vectors
#define VPT 2                                   // 16B vectors per copy thread
#define COPY_BLOCKS (N4 / (256 * VPT))          // 16224 (exact)
#define COPY_HALF1 (COPY_BLOCKS / 2)            // 8112
#define TOTAL_BLOCKS (COPY_BLOCKS + ASSIGN_BLOCKS)

typedef float v4f __attribute__((ext_vector_type(4)));  // native vector: ok for
                                                        // __builtin_nontemporal_*

__global__ __launch_bounds__(256) void fused_kernel(
    const v4f* __restrict__ img4,      // image as 16B vectors
    const float* __restrict__ bboxes,  // [64, 32, 4] pixel xywh (center)
    const int*   __restrict__ labels,  // [64, 32]
    float* __restrict__ out)           // d_out base
{
    const int tid = threadIdx.x;
    const int bid = blockIdx.x;

    if (bid < COPY_HALF1 || bid >= COPY_HALF1 + ASSIGN_BLOCKS) {
        // ---- image passthrough: plain cached loads (NT ablated — the one
        // untested knob on the dominant stream), NT stores (dead data, keep
        // out of L2). 2 × 16B per thread.
        const int cb = (bid < COPY_HALF1) ? bid : bid - ASSIGN_BLOCKS;
        v4f* dst4 = (v4f*)out;
        const int base = cb * (256 * VPT) + tid;
        v4f v[VPT];
        #pragma unroll
        for (int k = 0; k < VPT; ++k)
            v[k] = img4[base + k * 256];
        #pragma unroll
        for (int k = 0; k < VPT; ++k)
            __builtin_nontemporal_store(v[k], &dst4[base + k * 256]);
        return;
    }

    // ---- target assignment: one thread per cell, 32-box sequential scan ----
    const int ab    = bid - COPY_HALF1;
    const int b     = ab / ASSIGN_CHUNKS;
    const int chunk = ab % ASSIGN_CHUNKS;

    __shared__ float sbox[32][4];
    __shared__ int   slab[32];
    // LDS staging of the block's 256 cells × 25 channels → coalesced store.
    // st[t*25+ch]: stride-25 per thread, gcd(25,32)=1 → conflict-free writes.
    __shared__ float st[256 * 25];

    if (tid < 128) ((float*)sbox)[tid] = bboxes[b * 128 + tid];
    if (tid < 32)  slab[tid] = labels[b * 32 + tid];
    __syncthreads();

    const int c0 = chunk * 256;
    const int c  = c0 + tid;
    const bool valid = (c < CELLS_PER_IMG);

    if (valid) {
        int S, idx, scale_id;
        if (c < 169)      { S = 13; idx = c;       scale_id = 0; }
        else if (c < 845) { S = 26; idx = c - 169; scale_id = 1; }
        else              { S = 52; idx = c - 845; scale_id = 2; }

        const int i = idx % S;      // x index (scan dim 0; second spatial dim of output)
        const int j = idx / S;      // y index (scan dim 1; first spatial dim of output)
        const float stride = 416.0f / (float)S;   // 32, 16, 8 — exact
        const float inv    = 1.0f / stride;       // power of 2 — exact
        const float fi = (float)i, fj = (float)j;
        const float ci = (fi + 0.5f) * stride;    // pixel center, x
        const float cj = (fj + 0.5f) * stride;    // pixel center, y

        float reg0 = 0.f, reg1 = 0.f, reg2 = 0.f, reg3 = 0.f, reg4 = 0.f;
        unsigned clsmask = 0u;

        for (int n = 0; n < 32; ++n) {
            const float cx = sbox[n][0], cy = sbox[n][1];
            const float bw = sbox[n][2], bh = sbox[n][3];

            const float pos0 = floorf(cx * inv), pos1 = floorf(cy * inv);
            const float bp0  = floorf(0.5f * bw * inv), bp1 = floorf(0.5f * bh * inv);

            const bool region = (fi >= pos0 - bp0) && (fi < pos0 + bp0) &&
                                (fj >= pos1 - bp1) && (fj < pos1 + bp1);
            if (!region) continue;

            // cls[label] := 1 wherever region (independent of band)
            clsmask |= 1u << slab[n];

            const float hw = floorf(0.5f * bw), hh = floorf(0.5f * bh);
            const float L  = ci - (cx - hw);
            const float R  = (cx + hw) - ci;
            const float T  = cj - (cy - hh);
            const float Bo = (cy + hh) - cj;
            const float maxLR = fmaxf(L, R),  minLR = fminf(L, R);
            const float maxTB = fmaxf(T, Bo), minTB = fminf(T, Bo);
            const float m = fmaxf(maxLR, maxTB);

            const bool band = (scale_id == 0) ? (m > 256.0f)
                            : (scale_id == 1) ? (m > 64.0f && m <= 256.0f)
                            :                   (m <= 64.0f);
            if (!band) continue;

            // sequential tie-break: write if untouched or new m < stored channel-max
            const float regmax = fmaxf(fmaxf(fmaxf(reg0, reg1), fmaxf(reg2, reg3)), reg4);
            if (regmax == 0.0f || m < regmax) {
                const float cent = sqrtf((minLR * minTB) / (maxLR * maxTB));
                reg0 = fmaxf(L  * inv, 0.0f);
                reg1 = fmaxf(T  * inv, 0.0f);
                reg2 = fmaxf(R  * inv, 0.0f);
                reg3 = fmaxf(Bo * inv, 0.0f);
                reg4 = fmaxf(cent,     0.0f);
            }
        }

        // ch<20 one-hot cls, ch 20..24 = L,T,R,B (stride units) + centerness
        float* s = &st[tid * 25];
        #pragma unroll
        for (int ch = 0; ch < 20; ++ch)
            s[ch] = ((clsmask >> ch) & 1u) ? 1.0f : 0.0f;
        s[20] = reg0; s[21] = reg1; s[22] = reg2; s[23] = reg3; s[24] = reg4;
    }
    __syncthreads();

    // ---- cooperative coalesced store: chunk covers ≤3 contiguous output segments
    // (scale boundaries at c=169, 845). Within a scale, consecutive c → consecutive
    // 25-float records, so each segment is one contiguous global span.
    const int CS[3] = {0, 169, 845};
    const int CE[3] = {169, 845, CELLS_PER_IMG};
    const int SB[3] = {BASE13, BASE26, BASE52};
    const int SZ[3] = {169, 676, 2704};         // S*S
    const int c1 = (c0 + 256 < CELLS_PER_IMG) ? c0 + 256 : CELLS_PER_IMG;

    for (int sgi = 0; sgi < 3; ++sgi) {
        const int cs = (c0 > CS[sgi]) ? c0 : CS[sgi];
        const int ce = (c1 < CE[sgi]) ? c1 : CE[sgi];
        if (cs >= ce) continue;
        const size_t Gs = (size_t)IMG_ELEMS + SB[sgi] +
                          ((size_t)b * SZ[sgi] + (cs - CS[sgi])) * 25;
        const int   ls = (cs - c0) * 25;
        const int   Lf = (ce - cs) * 25;

        // head: dwords until 16B-aligned
        const int nh0 = (int)((4 - (Gs & 3)) & 3);
        const int nh  = (nh0 < Lf) ? nh0 : Lf;
        for (int f = tid; f < nh; f += 256)
            out[Gs + f] = st[ls + f];
        // body: aligned float4, nontemporal (dead data — don't dirty L2 under the
        // concurrent copy stream)
        const int nb = (Lf - nh) >> 2;
        const float* sp = &st[ls + nh];
        float* gp = out + Gs + nh;
        for (int q = tid; q < nb; q += 256) {
            v4f v;
            v.x = sp[4*q]; v.y = sp[4*q+1]; v.z = sp[4*q+2]; v.w = sp[4*q+3];
            __builtin_nontemporal_store(v, (v4f*)(gp + 4*q));
        }
        // tail
        for (int f = nh + 4*nb + tid; f < Lf; f += 256)
            out[Gs + f] = st[ls + f];
    }
}

extern "C" void kernel_launch(void* const* d_in, const int* in_sizes, int n_in,
                              void* d_out, int out_size, void* d_ws, size_t ws_size,
                              hipStream_t stream) {
    const float* image  = (const float*)d_in[0];  // [64,3,416,416]
    const float* bboxes = (const float*)d_in[1];  // [64,32,4]
    const int*   labels = (const int*)  d_in[2];  // [64,32]
    float* out = (float*)d_out;

    fused_kernel<<<dim3(TOTAL_BLOCKS), dim3(256), 0, stream>>>(
        (const v4f*)image, bboxes, labels, out);
}

// Round 4
// 244.890 us; speedup vs baseline: 1.0247x; 1.0247x over previous
//
#include <hip/hip_runtime.h>

// Output layout (float32, concatenated flat in reference return order):
//   [0]                image        64*3*416*416 = 33,226,752
//   [IMG_ELEMS]        targets@13   64*13*13*25  =    270,400
//   [.. + 270400]      targets@26   64*26*26*25  =  1,081,600
//   [.. + 1352000]     targets@52   64*52*52*25  =  4,326,400
#define IMG_ELEMS (64 * 3 * 416 * 416)
#define CELLS_PER_IMG (13*13 + 26*26 + 52*52)   // 3549
#define BASE13 0
#define BASE26 (64 * 169 * 25)                  // 270400
#define BASE52 (BASE26 + 64 * 676 * 25)         // 1352000

// Fused grid, "copy sandwich" scheduling (REVERTED to round-2 best config:
// NT loads + NT stores on the image stream, VPT=8, plain target stores.
// Round-3's bundle {plain loads, VPT=2, NT target stores} regressed ~10 µs.)
#define ASSIGN_CHUNKS 14                        // ceil(3549/256)
#define ASSIGN_BLOCKS (64 * ASSIGN_CHUNKS)      // 896
#define N4 (IMG_ELEMS / 4)                      // 8,306,688 16B-vectors
#define VPT 8                                   // 16B vectors per copy thread
#define COPY_BLOCKS (N4 / (256 * VPT))          // 4056 (exact)
#define COPY_HALF1 (COPY_BLOCKS / 2)            // 2028
#define TOTAL_BLOCKS (COPY_BLOCKS + ASSIGN_BLOCKS)

typedef float v4f __attribute__((ext_vector_type(4)));  // native vector: ok for
                                                        // __builtin_nontemporal_*

__global__ __launch_bounds__(256) void fused_kernel(
    const v4f* __restrict__ img4,      // image as 16B vectors
    const float* __restrict__ bboxes,  // [64, 32, 4] pixel xywh (center)
    const int*   __restrict__ labels,  // [64, 32]
    float* __restrict__ out)           // d_out base
{
    const int tid = threadIdx.x;
    const int bid = blockIdx.x;

    if (bid < COPY_HALF1 || bid >= COPY_HALF1 + ASSIGN_BLOCKS) {
        // ---- image passthrough: 8 × 16B per thread, nontemporal both ways ----
        const int cb = (bid < COPY_HALF1) ? bid : bid - ASSIGN_BLOCKS;
        v4f* dst4 = (v4f*)out;
        const int base = cb * (256 * VPT) + tid;
        v4f v[VPT];
        #pragma unroll
        for (int k = 0; k < VPT; ++k)
            v[k] = __builtin_nontemporal_load(&img4[base + k * 256]);
        #pragma unroll
        for (int k = 0; k < VPT; ++k)
            __builtin_nontemporal_store(v[k], &dst4[base + k * 256]);
        return;
    }

    // ---- target assignment: one thread per cell, 32-box sequential scan ----
    const int ab    = bid - COPY_HALF1;
    const int b     = ab / ASSIGN_CHUNKS;
    const int chunk = ab % ASSIGN_CHUNKS;

    __shared__ float sbox[32][4];
    __shared__ int   slab[32];
    // LDS staging of the block's 256 cells × 25 channels → coalesced store.
    // st[t*25+ch]: stride-25 per thread, gcd(25,32)=1 → conflict-free writes.
    __shared__ float st[256 * 25];

    if (tid < 128) ((float*)sbox)[tid] = bboxes[b * 128 + tid];
    if (tid < 32)  slab[tid] = labels[b * 32 + tid];
    __syncthreads();

    const int c0 = chunk * 256;
    const int c  = c0 + tid;
    const bool valid = (c < CELLS_PER_IMG);

    if (valid) {
        int S, idx, scale_id;
        if (c < 169)      { S = 13; idx = c;       scale_id = 0; }
        else if (c < 845) { S = 26; idx = c - 169; scale_id = 1; }
        else              { S = 52; idx = c - 845; scale_id = 2; }

        const int i = idx % S;      // x index (scan dim 0; second spatial dim of output)
        const int j = idx / S;      // y index (scan dim 1; first spatial dim of output)
        const float stride = 416.0f / (float)S;   // 32, 16, 8 — exact
        const float inv    = 1.0f / stride;       // power of 2 — exact
        const float fi = (float)i, fj = (float)j;
        const float ci = (fi + 0.5f) * stride;    // pixel center, x
        const float cj = (fj + 0.5f) * stride;    // pixel center, y

        float reg0 = 0.f, reg1 = 0.f, reg2 = 0.f, reg3 = 0.f, reg4 = 0.f;
        unsigned clsmask = 0u;

        for (int n = 0; n < 32; ++n) {
            const float cx = sbox[n][0], cy = sbox[n][1];
            const float bw = sbox[n][2], bh = sbox[n][3];

            const float pos0 = floorf(cx * inv), pos1 = floorf(cy * inv);
            const float bp0  = floorf(0.5f * bw * inv), bp1 = floorf(0.5f * bh * inv);

            const bool region = (fi >= pos0 - bp0) && (fi < pos0 + bp0) &&
                                (fj >= pos1 - bp1) && (fj < pos1 + bp1);
            if (!region) continue;

            // cls[label] := 1 wherever region (independent of band)
            clsmask |= 1u << slab[n];

            const float hw = floorf(0.5f * bw), hh = floorf(0.5f * bh);
            const float L  = ci - (cx - hw);
            const float R  = (cx + hw) - ci;
            const float T  = cj - (cy - hh);
            const float Bo = (cy + hh) - cj;
            const float maxLR = fmaxf(L, R),  minLR = fminf(L, R);
            const float maxTB = fmaxf(T, Bo), minTB = fminf(T, Bo);
            const float m = fmaxf(maxLR, maxTB);

            const bool band = (scale_id == 0) ? (m > 256.0f)
                            : (scale_id == 1) ? (m > 64.0f && m <= 256.0f)
                            :                   (m <= 64.0f);
            if (!band) continue;

            // sequential tie-break: write if untouched or new m < stored channel-max
            const float regmax = fmaxf(fmaxf(fmaxf(reg0, reg1), fmaxf(reg2, reg3)), reg4);
            if (regmax == 0.0f || m < regmax) {
                const float cent = sqrtf((minLR * minTB) / (maxLR * maxTB));
                reg0 = fmaxf(L  * inv, 0.0f);
                reg1 = fmaxf(T  * inv, 0.0f);
                reg2 = fmaxf(R  * inv, 0.0f);
                reg3 = fmaxf(Bo * inv, 0.0f);
                reg4 = fmaxf(cent,     0.0f);
            }
        }

        // ch<20 one-hot cls, ch 20..24 = L,T,R,B (stride units) + centerness
        float* s = &st[tid * 25];
        #pragma unroll
        for (int ch = 0; ch < 20; ++ch)
            s[ch] = ((clsmask >> ch) & 1u) ? 1.0f : 0.0f;
        s[20] = reg0; s[21] = reg1; s[22] = reg2; s[23] = reg3; s[24] = reg4;
    }
    __syncthreads();

    // ---- cooperative coalesced store: chunk covers ≤3 contiguous output segments
    // (scale boundaries at c=169, 845). Within a scale, consecutive c → consecutive
    // 25-float records, so each segment is one contiguous global span.
    const int CS[3] = {0, 169, 845};
    const int CE[3] = {169, 845, CELLS_PER_IMG};
    const int SB[3] = {BASE13, BASE26, BASE52};
    const int SZ[3] = {169, 676, 2704};         // S*S
    const int c1 = (c0 + 256 < CELLS_PER_IMG) ? c0 + 256 : CELLS_PER_IMG;

    for (int sgi = 0; sgi < 3; ++sgi) {
        const int cs = (c0 > CS[sgi]) ? c0 : CS[sgi];
        const int ce = (c1 < CE[sgi]) ? c1 : CE[sgi];
        if (cs >= ce) continue;
        const size_t Gs = (size_t)IMG_ELEMS + SB[sgi] +
                          ((size_t)b * SZ[sgi] + (cs - CS[sgi])) * 25;
        const int   ls = (cs - c0) * 25;
        const int   Lf = (ce - cs) * 25;

        // head: dwords until 16B-aligned
        const int nh0 = (int)((4 - (Gs & 3)) & 3);
        const int nh  = (nh0 < Lf) ? nh0 : Lf;
        for (int f = tid; f < nh; f += 256)
            out[Gs + f] = st[ls + f];
        // body: aligned float4
        const int nb = (Lf - nh) >> 2;
        const float* sp = &st[ls + nh];
        float* gp = out + Gs + nh;
        for (int q = tid; q < nb; q += 256) {
            v4f v;
            v.x = sp[4*q]; v.y = sp[4*q+1]; v.z = sp[4*q+2]; v.w = sp[4*q+3];
            *(v4f*)(gp + 4*q) = v;
        }
        // tail
        for (int f = nh + 4*nb + tid; f < Lf; f += 256)
            out[Gs + f] = st[ls + f];
    }
}

extern "C" void kernel_launch(void* const* d_in, const int* in_sizes, int n_in,
                              void* d_out, int out_size, void* d_ws, size_t ws_size,
                              hipStream_t stream) {
    const float* image  = (const float*)d_in[0];  // [64,3,416,416]
    const float* bboxes = (const float*)d_in[1];  // [64,32,4]
    const int*   labels = (const int*)  d_in[2];  // [64,32]
    float* out = (float*)d_out;

    fused_kernel<<<dim3(TOTAL_BLOCKS), dim3(256), 0, stream>>>(
        (const v4f*)image, bboxes, labels, out);
}